// Round 1
// baseline (200.654 us; speedup 1.0000x reference)
//
#include <hip/hip_runtime.h>

typedef __attribute__((ext_vector_type(8))) short bf16x8;
typedef __attribute__((ext_vector_type(4))) float f32x4;

// Swizzled byte address for 128-byte rows: XOR row bits into the 16B-slot index.
#define SWZ(row, byteofs) (((row)*128) + ((byteofs) ^ (((row)&7)<<4)))

__device__ __forceinline__ unsigned short f2bf(float x){
  unsigned u = __builtin_bit_cast(unsigned, x);
  u = (u + 0x7fffu + ((u >> 16) & 1u)) >> 16;
  return (unsigned short)u;
}

// ---------------- mask -> bitmask (1 bit per (q,k)) ----------------
__global__ __launch_bounds__(256) void mask_bits_kernel(const int* __restrict__ mask,
                                                        unsigned* __restrict__ bits){
  int t = blockIdx.x * 256 + threadIdx.x;
  int u = t >> 6;          // wave unit
  int lane = t & 63;
  int row = u >> 4;        // n*1024 + q   (0..8191)
  int chunk = u & 15;      // 64 keys per unit
  int m = mask[(size_t)row * 1024 + chunk * 64 + lane];
  unsigned long long b = __ballot(m != 0);
  if (lane == 0){
    unsigned* p = bits + row * 32 + chunk * 2;
    p[0] = (unsigned)(b & 0xffffffffull);
    p[1] = (unsigned)(b >> 32);
  }
}

// ---------------- W fp32 -> bf16 ----------------
__global__ __launch_bounds__(256) void wconv_kernel(const float* __restrict__ W,
                                                    unsigned short* __restrict__ Wb){
  int i = blockIdx.x * 256 + threadIdx.x;        // one float4 per thread
  float4 f = reinterpret_cast<const float4*>(W)[i];
  ushort4 o;
  o.x = f2bf(f.x); o.y = f2bf(f.y); o.z = f2bf(f.z); o.w = f2bf(f.w);
  reinterpret_cast<ushort4*>(Wb)[i] = o;
}

// ---------------- flash attention ----------------
// grid: 2048 blocks = (n:8) x (h:16) x (qb:16), 256 threads (4 waves x 16 q-rows)
__global__ __launch_bounds__(256) void attn_kernel(
    const float* __restrict__ Q, const float* __restrict__ K, const float* __restrict__ V,
    const unsigned* __restrict__ bits, unsigned short* __restrict__ Obf)
{
  __shared__ __attribute__((aligned(16))) unsigned short Kt[64*64];     // [key][d] bf16, swizzled
  __shared__ __attribute__((aligned(16))) unsigned short Vt[64*64];     // [d][key] bf16, swizzled
  __shared__ __attribute__((aligned(16))) unsigned short Pl[4][16*64];  // per-wave P, swizzled

  int bid = blockIdx.x;
  int wg = ((bid & 7) << 8) | (bid >> 3);   // XCD-contiguous chunks of 256
  int qb = wg & 15;
  int h  = (wg >> 4) & 15;
  int n  = wg >> 8;

  int tid  = threadIdx.x;
  int wid  = tid >> 6;
  int lane = tid & 63;
  int lg   = lane >> 4;
  int lc   = lane & 15;

  int qbase = qb * 64 + wid * 16;
  const size_t nhbase = (size_t)n * 1024 * 1024 + (size_t)h * 64;

  // Q A-fragments: lane holds Q[row=lc][k = lg*8 + j + 32*c]
  bf16x8 qf[2];
  {
    const float* qp = Q + (size_t)(n*1024 + qbase + lc) * 1024 + h*64;
    for (int c = 0; c < 2; ++c){
      float4 a0 = *reinterpret_cast<const float4*>(qp + c*32 + lg*8);
      float4 a1 = *reinterpret_cast<const float4*>(qp + c*32 + lg*8 + 4);
      bf16x8 v;
      v[0]=(short)f2bf(a0.x); v[1]=(short)f2bf(a0.y); v[2]=(short)f2bf(a0.z); v[3]=(short)f2bf(a0.w);
      v[4]=(short)f2bf(a1.x); v[5]=(short)f2bf(a1.y); v[6]=(short)f2bf(a1.z); v[7]=(short)f2bf(a1.w);
      qf[c] = v;
    }
  }

  f32x4 acc[4];
  for (int i = 0; i < 4; ++i) acc[i] = (f32x4){0.f,0.f,0.f,0.f};
  float mrow[4] = {-1e30f,-1e30f,-1e30f,-1e30f};
  float lrow[4] = {0.f,0.f,0.f,0.f};
  const float scale = 0.03125f;   // 1/sqrt(1024)

  for (int kb = 0; kb < 16; ++kb){
    __syncthreads();
    // ---- stage K tile (64 keys x 64 d) fp32->bf16 ----
    {
      int row = tid >> 2;          // key
      int seg = tid & 3;           // 16-float segment of d
      const float* kp = K + nhbase + (size_t)(kb*64 + row) * 1024 + seg*16;
      bf16x8 lo, hi;
      {
        float4 f0 = *reinterpret_cast<const float4*>(kp + 0);
        float4 f1 = *reinterpret_cast<const float4*>(kp + 4);
        lo[0]=(short)f2bf(f0.x); lo[1]=(short)f2bf(f0.y); lo[2]=(short)f2bf(f0.z); lo[3]=(short)f2bf(f0.w);
        lo[4]=(short)f2bf(f1.x); lo[5]=(short)f2bf(f1.y); lo[6]=(short)f2bf(f1.z); lo[7]=(short)f2bf(f1.w);
        float4 f2 = *reinterpret_cast<const float4*>(kp + 8);
        float4 f3 = *reinterpret_cast<const float4*>(kp + 12);
        hi[0]=(short)f2bf(f2.x); hi[1]=(short)f2bf(f2.y); hi[2]=(short)f2bf(f2.z); hi[3]=(short)f2bf(f2.w);
        hi[4]=(short)f2bf(f3.x); hi[5]=(short)f2bf(f3.y); hi[6]=(short)f2bf(f3.z); hi[7]=(short)f2bf(f3.w);
      }
      *reinterpret_cast<bf16x8*>((char*)Kt + SWZ(row, seg*32))      = lo;
      *reinterpret_cast<bf16x8*>((char*)Kt + SWZ(row, seg*32 + 16)) = hi;
    }
    // ---- stage V^T tile: Vt[d][key] ----
    {
      int key = tid >> 2;
      int dbase = (tid & 3) * 16;
      const float* vp = V + nhbase + (size_t)(kb*64 + key) * 1024 + dbase;
      for (int i = 0; i < 4; ++i){
        float4 f = *reinterpret_cast<const float4*>(vp + i*4);
        *(unsigned short*)((char*)Vt + SWZ(dbase+i*4+0, key*2)) = f2bf(f.x);
        *(unsigned short*)((char*)Vt + SWZ(dbase+i*4+1, key*2)) = f2bf(f.y);
        *(unsigned short*)((char*)Vt + SWZ(dbase+i*4+2, key*2)) = f2bf(f.z);
        *(unsigned short*)((char*)Vt + SWZ(dbase+i*4+3, key*2)) = f2bf(f.w);
      }
    }
    __syncthreads();

    // ---- S = Q . K^T  (16 q x 64 keys, 4 key tiles) ----
    f32x4 S[4];
    for (int t = 0; t < 4; ++t) S[t] = (f32x4){0.f,0.f,0.f,0.f};
    for (int t = 0; t < 4; ++t)
      for (int c = 0; c < 2; ++c){
        bf16x8 kf = *reinterpret_cast<const bf16x8*>((const char*)Kt + SWZ(t*16 + lc, lg*16 + c*64));
        S[t] = __builtin_amdgcn_mfma_f32_16x16x32_bf16(qf[c], kf, S[t], 0, 0, 0);
      }

    // ---- mask + scale (masked -> logit 0.0, faithful to 1e-20/32 quirk) ----
    unsigned words[4][2];
    {
      const unsigned* bp = bits + (size_t)(n*1024 + qbase + lg*4) * 32 + kb*2;
      for (int r = 0; r < 4; ++r){ words[r][0] = bp[r*32]; words[r][1] = bp[r*32 + 1]; }
    }
    float p[4][4];
    for (int t = 0; t < 4; ++t){
      int bitidx = ((t & 1) << 4) + lc;
      for (int r = 0; r < 4; ++r){
        bool mk = (words[r][t>>1] >> bitidx) & 1u;
        p[t][r] = mk ? S[t][r] * scale : 0.0f;
      }
    }

    // ---- online softmax (row q = lg*4 + r lives in 16-lane group lg) ----
    for (int r = 0; r < 4; ++r){
      float mx = fmaxf(fmaxf(p[0][r], p[1][r]), fmaxf(p[2][r], p[3][r]));
      for (int d = 1; d < 16; d <<= 1) mx = fmaxf(mx, __shfl_xor(mx, d, 64));
      float mnew = fmaxf(mrow[r], mx);
      float corr = __expf(mrow[r] - mnew);
      mrow[r] = mnew;
      float s = 0.f;
      for (int t = 0; t < 4; ++t){ p[t][r] = __expf(p[t][r] - mnew); s += p[t][r]; }
      for (int d = 1; d < 16; d <<= 1) s += __shfl_xor(s, d, 64);
      lrow[r] = lrow[r] * corr + s;
      acc[0][r] *= corr; acc[1][r] *= corr; acc[2][r] *= corr; acc[3][r] *= corr;
    }

    // ---- P -> bf16 -> per-wave LDS (A-fragment relayout) ----
    unsigned short* pl = &Pl[wid][0];
    for (int t = 0; t < 4; ++t)
      for (int r = 0; r < 4; ++r)
        *(unsigned short*)((char*)pl + SWZ(lg*4 + r, (t*16 + lc)*2)) = f2bf(p[t][r]);

    // ---- O += P . V ----
    for (int kc = 0; kc < 2; ++kc){
      bf16x8 af = *reinterpret_cast<const bf16x8*>((const char*)pl + SWZ(lc, lg*16 + kc*64));
      for (int t2 = 0; t2 < 4; ++t2){
        bf16x8 vf = *reinterpret_cast<const bf16x8*>((const char*)Vt + SWZ(t2*16 + lc, lg*16 + kc*64));
        acc[t2] = __builtin_amdgcn_mfma_f32_16x16x32_bf16(af, vf, acc[t2], 0, 0, 0);
      }
    }
  }

  // ---- normalize + store O as bf16 (layout n,q,h,d) ----
  for (int r = 0; r < 4; ++r){
    float inv = 1.0f / lrow[r];
    size_t qg = (size_t)(n*1024 + qbase + lg*4 + r);
    unsigned short* op = Obf + (qg * 16 + h) * 64;
    for (int t2 = 0; t2 < 4; ++t2)
      op[t2*16 + lc] = f2bf(acc[t2][r] * inv);
  }
}

// ---------------- out = O @ W^T + b   (8192x1024x1024 bf16 GEMM) ----------------
__global__ __launch_bounds__(256) void out_gemm_kernel(
    const unsigned short* __restrict__ A, const unsigned short* __restrict__ B,
    const float* __restrict__ bias, float* __restrict__ out)
{
  __shared__ __attribute__((aligned(16))) unsigned short As[128*64];
  __shared__ __attribute__((aligned(16))) unsigned short Bs[128*64];

  int mb = blockIdx.x;     // 64
  int nb = blockIdx.y;     // 8
  int tid = threadIdx.x, wid = tid >> 6, lane = tid & 63, lg = lane >> 4, lc = lane & 15;
  int wr = wid >> 1, wc = wid & 1;

  f32x4 acc[4][4];
  for (int m = 0; m < 4; ++m)
    for (int nn2 = 0; nn2 < 4; ++nn2) acc[m][nn2] = (f32x4){0.f,0.f,0.f,0.f};

  for (int kb = 0; kb < 16; ++kb){
    __syncthreads();
    {
      int row = tid >> 1;
      int half = tid & 1;
      const unsigned short* ap = A + (size_t)(mb*128 + row) * 1024 + kb*64 + half*32;
      const unsigned short* bp = B + (size_t)(nb*128 + row) * 1024 + kb*64 + half*32;
      for (int j = 0; j < 4; ++j){
        *reinterpret_cast<bf16x8*>((char*)As + SWZ(row, half*64 + j*16)) = *reinterpret_cast<const bf16x8*>(ap + j*8);
        *reinterpret_cast<bf16x8*>((char*)Bs + SWZ(row, half*64 + j*16)) = *reinterpret_cast<const bf16x8*>(bp + j*8);
      }
    }
    __syncthreads();
    for (int kc = 0; kc < 2; ++kc){
      bf16x8 af[4], bfr[4];
      for (int m = 0; m < 4; ++m)
        af[m] = *reinterpret_cast<const bf16x8*>((const char*)As + SWZ(wr*64 + m*16 + lc, kc*64 + lg*16));
      for (int nn2 = 0; nn2 < 4; ++nn2)
        bfr[nn2] = *reinterpret_cast<const bf16x8*>((const char*)Bs + SWZ(wc*64 + nn2*16 + lc, kc*64 + lg*16));
      for (int m = 0; m < 4; ++m)
        for (int nn2 = 0; nn2 < 4; ++nn2)
          acc[m][nn2] = __builtin_amdgcn_mfma_f32_16x16x32_bf16(af[m], bfr[nn2], acc[m][nn2], 0, 0, 0);
    }
  }

  for (int nn2 = 0; nn2 < 4; ++nn2){
    int col = nb*128 + wc*64 + nn2*16 + lc;
    float bv = bias[col];
    for (int m = 0; m < 4; ++m){
      int rowb = mb*128 + wr*64 + m*16 + lg*4;
      for (int r = 0; r < 4; ++r)
        out[(size_t)(rowb + r) * 1024 + col] = acc[m][nn2][r] + bv;
    }
  }
}

extern "C" void kernel_launch(void* const* d_in, const int* in_sizes, int n_in,
                              void* d_out, int out_size, void* d_ws, size_t ws_size,
                              hipStream_t stream) {
  const float* V  = (const float*)d_in[0];
  const float* K  = (const float*)d_in[1];
  const float* Q  = (const float*)d_in[2];
  const int* mask = (const int*)d_in[3];
  const float* W  = (const float*)d_in[4];
  const float* b  = (const float*)d_in[5];
  float* out = (float*)d_out;

  char* ws = (char*)d_ws;
  unsigned* bits      = (unsigned*)ws;                 // 1 MB
  unsigned short* Wb  = (unsigned short*)(ws + (1u<<20));  // 2 MB
  unsigned short* Obf = (unsigned short*)(ws + (3u<<20));  // 16 MB

  mask_bits_kernel<<<32768, 256, 0, stream>>>(mask, bits);
  wconv_kernel<<<1024, 256, 0, stream>>>(W, Wb);
  attn_kernel<<<2048, 256, 0, stream>>>(Q, K, V, bits, Obf);
  dim3 g(64, 8);
  out_gemm_kernel<<<g, 256, 0, stream>>>(Obf, Wb, b, out);
}